// Round 21
// baseline (56.454 us; speedup 1.0000x reference)
//
#include <hip/hip_runtime.h>
#include <hip/hip_bf16.h>

typedef __attribute__((ext_vector_type(4))) short bf16x4;   // 4 bf16 = 2 VGPR
typedef __attribute__((ext_vector_type(4))) float f32x4;
typedef __attribute__((ext_vector_type(4))) int i32x4;

#define LOG2E 1.4426950408889634f
#define SMAX 8.0f   // fixed softmax shift (log2 domain); exact after normalization

static __device__ inline f32x4 mfma16(bf16x4 a, bf16x4 b, f32x4 c) {
  return __builtin_amdgcn_mfma_f32_16x16x16bf16_1k(a, b, c, 0, 0, 0);
}
static __device__ inline ushort f2bfu(float f) {
  __hip_bfloat16 h = __float2bfloat16(f);
  return *(ushort*)&h;
}
static __device__ __forceinline__ void dma16(const void* g, void* l) {
  __builtin_amdgcn_global_load_lds(
      (const __attribute__((address_space(1))) void*)g,
      (__attribute__((address_space(3))) void*)l, 16, 0, 0);
}

// ---------------------------------------------------------------------------
// x prep: xb[i] = bf16(x[i]), 1M elements. Coalesced f32x4 -> bf16x4 stream.
// ---------------------------------------------------------------------------
__global__ __launch_bounds__(256) void prep_x(
    const float* __restrict__ x, ushort* __restrict__ xb) {
  const size_t i = ((size_t)blockIdx.x * 256 + threadIdx.x) * 4;
  f32x4 v = *(const f32x4*)(x + i);
  bf16x4 o;
  o[0] = (short)f2bfu(v[0]); o[1] = (short)f2bfu(v[1]);
  o[2] = (short)f2bfu(v[2]); o[3] = (short)f2bfu(v[3]);
  *(bf16x4*)(xb + i) = o;
}

// ---------------------------------------------------------------------------
// Fused QKV projections (r20 structure; DELTA: A-side from pre-converted
// bf16 xb -> one 8B load, no per-tile conversions). grid 3072 x 256.
// Q: row-major scaled 0.25*log2e. K: Kt[((b8+h)*1024+n)*16+k].
// V: Vt[((b8+h)*16+(n>>6))*1024 + d*64 + (n&63)].
// ---------------------------------------------------------------------------
__global__ __launch_bounds__(256) void gemm_qkv(
    const ushort* __restrict__ xb,
    const float* __restrict__ Wq, const float* __restrict__ bq,
    const float* __restrict__ Wk, const float* __restrict__ bk,
    const float* __restrict__ Wv, const float* __restrict__ bv,
    ushort* __restrict__ Qs, ushort* __restrict__ Kt, ushort* __restrict__ Vt) {
  const int which = blockIdx.x >> 10;       // 0=Q 1=K 2=V
  const int bid = blockIdx.x & 1023;
  const int tid = threadIdx.x;
  const int l = tid & 63, w = tid >> 6;
  const int lm = l & 15, g = l >> 4;
  const int tile = bid * 4 + w;
  const int mt = tile >> 3, nt = tile & 7;
  const int row = mt * 16 + lm;
  const int col = nt * 16 + lm;

  const float* W = (which == 0) ? Wq : (which == 1) ? Wk : Wv;
  const float* bias = (which == 0) ? bq : (which == 1) ? bk : bv;

  f32x4 acc = {0.f, 0.f, 0.f, 0.f};
#pragma unroll
  for (int ks = 0; ks < 8; ++ks) {
    bf16x4 a = *(const bf16x4*)(xb + (size_t)row * 128 + ks * 16 + g * 4);
    const float* wp = W + (size_t)(ks * 16 + g * 4) * 128 + col;
    bf16x4 b;
    b[0] = (short)f2bfu(wp[0]);   b[1] = (short)f2bfu(wp[128]);
    b[2] = (short)f2bfu(wp[256]); b[3] = (short)f2bfu(wp[384]);
    acc = mfma16(a, b, acc);
  }
  const float bv_ = bias[col];
  const float alpha = (which == 0) ? 0.25f * LOG2E : 1.0f;
  float v0 = (acc[0] + bv_) * alpha, v1 = (acc[1] + bv_) * alpha;
  float v2 = (acc[2] + bv_) * alpha, v3 = (acc[3] + bv_) * alpha;
  const int mb = mt * 16;

  if (which == 0) {
    Qs[(size_t)(mb + g * 4 + 0) * 128 + col] = f2bfu(v0);
    Qs[(size_t)(mb + g * 4 + 1) * 128 + col] = f2bfu(v1);
    Qs[(size_t)(mb + g * 4 + 2) * 128 + col] = f2bfu(v2);
    Qs[(size_t)(mb + g * 4 + 3) * 128 + col] = f2bfu(v3);
  } else if (which == 1) {
    const size_t kb = ((size_t)((mb >> 10) * 8 + nt) * 1024 + ((mb & 1023) + g * 4));
    Kt[(kb + 0) * 16 + lm] = f2bfu(v0);
    Kt[(kb + 1) * 16 + lm] = f2bfu(v1);
    Kt[(kb + 2) * 16 + lm] = f2bfu(v2);
    Kt[(kb + 3) * 16 + lm] = f2bfu(v3);
  } else {
    const size_t addr = ((size_t)((mb >> 10) * 8 + nt) * 16 + ((mb & 1023) >> 6)) * 1024
                        + (size_t)lm * 64 + (mb & 63) + g * 4;
    bf16x4 vv;
    vv[0] = (short)f2bfu(v0); vv[1] = (short)f2bfu(v1);
    vv[2] = (short)f2bfu(v2); vv[3] = (short)f2bfu(v3);
    *(bf16x4*)(Vt + addr) = vv;
  }
}

// ---------------------------------------------------------------------------
// Fused attention + output projection (r20-verified, byte-identical).
// One WG = (b, 32-row group); 8 waves = 8 heads; 16 tiles x 64 cols;
// 6 DMAs/wave/tile; counted vmcnt(6); 2 buffers x 48 KB; lsum via MFMA.
// ---------------------------------------------------------------------------
#define BUFB 49152  // per buffer: K 16K | V 16K | adj 8K | edge 8K

__global__ __launch_bounds__(512) void attn_kernel(
    const ushort* __restrict__ Qs, const ushort* __restrict__ Kt,
    const ushort* __restrict__ Vt, const int* __restrict__ adj,
    const float* __restrict__ edge, const float* __restrict__ We,
    const float* __restrict__ Wo, const float* __restrict__ bo,
    float* __restrict__ out) {
  __shared__ __align__(16) char smem[2 * BUFB];

  const int tid = threadIdx.x;
  const int l = tid & 63, h = tid >> 6;
  const int lm = l & 15, g = l >> 4;
  const int b = blockIdx.x >> 5;          // 8 batches
  const int m0 = (blockIdx.x & 31) * 32;  // 32 row-groups of 32 rows

  const float Weh = We[h] * LOG2E;
  bf16x4 qf0 = *(const bf16x4*)(Qs + ((size_t)b * 1024 + m0 + lm) * 128 + h * 16 + g * 4);
  bf16x4 qf1 = *(const bf16x4*)(Qs + ((size_t)b * 1024 + m0 + 16 + lm) * 128 + h * 16 + g * 4);

  const ushort* kt0 = Kt + ((size_t)b * 8 + h) * 16384 + l * 8;
  const int dv = l >> 3, mv = l & 7;
  const int voff = dv * 64 + (((mv * 2) ^ (dv & 6)) * 4);
  const ushort* vt0 = Vt + ((size_t)b * 8 + h) * 16384 + voff;

  const int hh = h & 3;
  const int d0 = hh * 2, d1 = d0 + 1;
  const int row0 = 4 * d0 + (l >> 4), row1 = 4 * d1 + (l >> 4);
  const int gr0 = (l & 15) ^ ((row0 & 7) << 1);
  const int gr1 = (l & 15) ^ ((row1 & 7) << 1);
  const int* sbase = ((h < 4) ? adj : (const int*)edge)
                     + (size_t)b * 1048576 + (size_t)m0 * 1024;
  const int* ssrc0 = sbase + (size_t)row0 * 1024 + gr0 * 4;
  const int* ssrc1 = sbase + (size_t)row1 * 1024 + gr1 * 4;

  char* kdst = smem + h * 2048;
  char* vdst = smem + 16384 + h * 2048;
  char* sreg = smem + ((h < 4) ? 32768 : 40960);
  char* sdst0 = sreg + d0 * 1024;
  char* sdst1 = sreg + d1 * 1024;

  f32x4 oacc0 = {0.f, 0.f, 0.f, 0.f}, oacc1 = {0.f, 0.f, 0.f, 0.f};
  f32x4 lacc0 = {0.f, 0.f, 0.f, 0.f}, lacc1 = {0.f, 0.f, 0.f, 0.f};
  const f32x4 cinit = {-SMAX, -SMAX, -SMAX, -SMAX};
  const short ONE = (short)0x3F80;               // bf16 1.0
  const bf16x4 ones = {ONE, ONE, ONE, ONE};

  auto stage = [&](int T) {
    const int bo_ = (T & 1) * BUFB;
    const ushort* ks = kt0 + (size_t)T * 1024;
    const ushort* vs = vt0 + (size_t)T * 1024;
    dma16(ks,        kdst + bo_);
    dma16(ks + 512,  kdst + bo_ + 1024);
    dma16(vs,        vdst + bo_);
    dma16(vs + 512,  vdst + bo_ + 1024);
    dma16(ssrc0 + T * 64, sdst0 + bo_);
    dma16(ssrc1 + T * 64, sdst1 + bo_);
  };

  auto compute = [&](int bi) {
    const char* base = smem + bi * BUFB;
    const char* kls = base + h * 2048;
    const char* vls = base + 16384 + h * 2048;
    const int* als = (const int*)(base + 32768);
    const int* els = (const int*)(base + 40960);
    const int xorv = (lm & 7) << 3;

    bf16x4 kf[4], vfr[4];
#pragma unroll
    for (int t = 0; t < 4; ++t) {
      kf[t]  = *(const bf16x4*)(kls + (t * 16 + lm) * 32 + g * 8);
      vfr[t] = *(const bf16x4*)(vls + lm * 128 + (((t * 4 + g) ^ (lm & 6)) * 8));
    }
#pragma unroll
    for (int s = 0; s < 2; ++s) {
      const bf16x4 qf = s ? qf1 : qf0;
      f32x4 st[4];
#pragma unroll
      for (int t = 0; t < 4; ++t) st[t] = mfma16(kf[t], qf, cinit);
      f32x4 oac = s ? oacc1 : oacc0;
      f32x4 pac = s ? lacc1 : lacc0;
#pragma unroll
      for (int t = 0; t < 4; ++t) {
        const int ci = (t * 16 + g * 4) ^ xorv;
        const int ro = (16 * s + lm) * 64;
        const i32x4 a4 = *(const i32x4*)(als + ro + ci);
        const i32x4 e4i = *(const i32x4*)(els + ro + ci);
        const f32x4 e4 = *(const f32x4*)&e4i;
        bf16x4 pf4;
#pragma unroll
        for (int j = 0; j < 4; ++j) {
          float p = __builtin_amdgcn_exp2f(fmaf(e4[j], Weh, st[t][j]));
          p = (a4[j] == 0) ? 0.f : p;
          pf4[j] = (short)f2bfu(p);
        }
        oac = mfma16(vfr[t], pf4, oac);   // O^T[d=4g+r][m=lm]
        pac = mfma16(ones,   pf4, pac);   // col-sum of P (all rows equal)
      }
      if (s) { oacc1 = oac; lacc1 = pac; } else { oacc0 = oac; lacc0 = pac; }
    }
  };

  stage(0);
  stage(1);

  for (int ct = 0; ct < 15; ++ct) {
    asm volatile("s_waitcnt vmcnt(6)" ::: "memory");
    __builtin_amdgcn_s_barrier();
    __builtin_amdgcn_sched_barrier(0);
    compute(ct & 1);
    __builtin_amdgcn_s_barrier();
    __builtin_amdgcn_sched_barrier(0);
    if (ct < 14) stage(ct + 2);
  }
  asm volatile("s_waitcnt vmcnt(0)" ::: "memory");
  __builtin_amdgcn_s_barrier();
  __builtin_amdgcn_sched_barrier(0);
  compute(1);

  // ---- epilogue: normalize (lsum = lacc[0]), AO -> LDS, out = AO@Wo + bo ----
  const float inv0 = 1.0f / lacc0[0];
  const float inv1 = 1.0f / lacc1[0];

  __syncthreads();
  ushort* aot = (ushort*)smem;   // 32 x 132 bf16
  {
    bf16x4 ov;
    ov[0] = (short)f2bfu(oacc0[0] * inv0);
    ov[1] = (short)f2bfu(oacc0[1] * inv0);
    ov[2] = (short)f2bfu(oacc0[2] * inv0);
    ov[3] = (short)f2bfu(oacc0[3] * inv0);
    *(bf16x4*)(aot + (lm) * 132 + h * 16 + g * 4) = ov;
    ov[0] = (short)f2bfu(oacc1[0] * inv1);
    ov[1] = (short)f2bfu(oacc1[1] * inv1);
    ov[2] = (short)f2bfu(oacc1[2] * inv1);
    ov[3] = (short)f2bfu(oacc1[3] * inv1);
    *(bf16x4*)(aot + (16 + lm) * 132 + h * 16 + g * 4) = ov;
  }
  __syncthreads();

  f32x4 acc0 = {0.f, 0.f, 0.f, 0.f}, acc1 = {0.f, 0.f, 0.f, 0.f};
#pragma unroll
  for (int ks = 0; ks < 8; ++ks) {
    const float* wp = Wo + (size_t)(ks * 16 + g * 4) * 128 + h * 16 + lm;
    bf16x4 bfr;
    bfr[0] = (short)f2bfu(wp[0]);   bfr[1] = (short)f2bfu(wp[128]);
    bfr[2] = (short)f2bfu(wp[256]); bfr[3] = (short)f2bfu(wp[384]);
    bf16x4 a0 = *(const bf16x4*)(aot + lm * 132 + ks * 16 + g * 4);
    bf16x4 a1 = *(const bf16x4*)(aot + (16 + lm) * 132 + ks * 16 + g * 4);
    acc0 = mfma16(a0, bfr, acc0);
    acc1 = mfma16(a1, bfr, acc1);
  }
  const float bv = bo[h * 16 + lm];
  float* op0 = out + ((size_t)b * 1024 + m0 + g * 4) * 128 + h * 16 + lm;
  float* op1 = op0 + 16 * 128;
  op0[0 * 128] = acc0[0] + bv;
  op0[1 * 128] = acc0[1] + bv;
  op0[2 * 128] = acc0[2] + bv;
  op0[3 * 128] = acc0[3] + bv;
  op1[0 * 128] = acc1[0] + bv;
  op1[1 * 128] = acc1[1] + bv;
  op1[2 * 128] = acc1[2] + bv;
  op1[3 * 128] = acc1[3] + bv;
}

extern "C" void kernel_launch(void* const* d_in, const int* in_sizes, int n_in,
                              void* d_out, int out_size, void* d_ws, size_t ws_size,
                              hipStream_t stream) {
  const float* x   = (const float*)d_in[0];
  const int*   adj = (const int*)d_in[1];
  const float* ew  = (const float*)d_in[2];
  const float* Wq  = (const float*)d_in[3];
  const float* bq  = (const float*)d_in[4];
  const float* Wk  = (const float*)d_in[5];
  const float* bk  = (const float*)d_in[6];
  const float* Wv  = (const float*)d_in[7];
  const float* bv  = (const float*)d_in[8];
  const float* Wo  = (const float*)d_in[9];
  const float* bo  = (const float*)d_in[10];
  const float* We  = (const float*)d_in[11];
  // be (d_in[12]) dropped: softmax(x + c) == softmax(x)

  const size_t MN = (size_t)8 * 1024 * 128;  // 1M elements
  ushort* Qs = (ushort*)d_ws;
  ushort* Kt = Qs + MN;
  ushort* Vt = Kt + MN;
  ushort* xb = Vt + MN;   // 1M bf16

  prep_x<<<1024, 256, 0, stream>>>(x, xb);
  gemm_qkv<<<3072, 256, 0, stream>>>(xb, Wq, bq, Wk, bk, Wv, bv, Qs, Kt, Vt);
  attn_kernel<<<256, 512, 0, stream>>>(Qs, Kt, Vt, adj, ew, We, Wo, bo, (float*)d_out);
}

// Round 22
// 50.086 us; speedup vs baseline: 1.1272x; 1.1272x over previous
//
#include <hip/hip_runtime.h>
#include <hip/hip_bf16.h>

typedef __attribute__((ext_vector_type(4))) short bf16x4;   // 4 bf16 = 2 VGPR
typedef __attribute__((ext_vector_type(4))) float f32x4;
typedef __attribute__((ext_vector_type(4))) int i32x4;

#define LOG2E 1.4426950408889634f
#define SMAX 8.0f   // fixed softmax shift (log2 domain); exact after normalization

static __device__ inline f32x4 mfma16(bf16x4 a, bf16x4 b, f32x4 c) {
  return __builtin_amdgcn_mfma_f32_16x16x16bf16_1k(a, b, c, 0, 0, 0);
}
static __device__ inline ushort f2bfu(float f) {
  __hip_bfloat16 h = __float2bfloat16(f);
  return *(ushort*)&h;
}
static __device__ __forceinline__ void dma16(const void* g, void* l) {
  __builtin_amdgcn_global_load_lds(
      (const __attribute__((address_space(1))) void*)g,
      (__attribute__((address_space(3))) void*)l, 16, 0, 0);
}

// ---------------------------------------------------------------------------
// Fused QKV projections. DELTA vs r20: each wave computes TWO row-subtiles
// (rows mt2*32 and mt2*32+16) for one column tile, reusing the B-fragment
// (the expensive 4-strided-load + cvt stream) across both. grid 1536 x 256.
// Q: row-major scaled 0.25*log2e. K: Kt[((b8+h)*1024+n)*16+k].
// V: Vt[((b8+h)*16+(n>>6))*1024 + d*64 + (n&63)].
// ---------------------------------------------------------------------------
__global__ __launch_bounds__(256) void gemm_qkv(
    const float* __restrict__ x,
    const float* __restrict__ Wq, const float* __restrict__ bq,
    const float* __restrict__ Wk, const float* __restrict__ bk,
    const float* __restrict__ Wv, const float* __restrict__ bv,
    ushort* __restrict__ Qs, ushort* __restrict__ Kt, ushort* __restrict__ Vt) {
  const int which = blockIdx.x >> 9;        // 0=Q 1=K 2=V (512 blocks each)
  const int bid = blockIdx.x & 511;
  const int tid = threadIdx.x;
  const int l = tid & 63, w = tid >> 6;
  const int lm = l & 15, g = l >> 4;
  const int task = bid * 4 + w;             // 0..2047
  const int mt2 = task >> 3, nt = task & 7; // 256 row-pairs x 8 col tiles
  const int row0 = mt2 * 32 + lm;
  const int row1 = row0 + 16;
  const int col = nt * 16 + lm;

  const float* W = (which == 0) ? Wq : (which == 1) ? Wk : Wv;
  const float* bias = (which == 0) ? bq : (which == 1) ? bk : bv;

  f32x4 acc0 = {0.f, 0.f, 0.f, 0.f}, acc1 = {0.f, 0.f, 0.f, 0.f};
#pragma unroll
  for (int ks = 0; ks < 8; ++ks) {
    const float* wp = W + (size_t)(ks * 16 + g * 4) * 128 + col;
    bf16x4 bfr;
    bfr[0] = (short)f2bfu(wp[0]);   bfr[1] = (short)f2bfu(wp[128]);
    bfr[2] = (short)f2bfu(wp[256]); bfr[3] = (short)f2bfu(wp[384]);

    f32x4 av0 = *(const f32x4*)(x + (size_t)row0 * 128 + ks * 16 + g * 4);
    f32x4 av1 = *(const f32x4*)(x + (size_t)row1 * 128 + ks * 16 + g * 4);
    bf16x4 a0, a1;
    a0[0] = (short)f2bfu(av0[0]); a0[1] = (short)f2bfu(av0[1]);
    a0[2] = (short)f2bfu(av0[2]); a0[3] = (short)f2bfu(av0[3]);
    a1[0] = (short)f2bfu(av1[0]); a1[1] = (short)f2bfu(av1[1]);
    a1[2] = (short)f2bfu(av1[2]); a1[3] = (short)f2bfu(av1[3]);

    acc0 = mfma16(a0, bfr, acc0);
    acc1 = mfma16(a1, bfr, acc1);
  }
  const float bv_ = bias[col];
  const float alpha = (which == 0) ? 0.25f * LOG2E : 1.0f;

#pragma unroll
  for (int s = 0; s < 2; ++s) {
    const f32x4 acc = s ? acc1 : acc0;
    const int mb = mt2 * 32 + s * 16;
    float v0 = (acc[0] + bv_) * alpha, v1 = (acc[1] + bv_) * alpha;
    float v2 = (acc[2] + bv_) * alpha, v3 = (acc[3] + bv_) * alpha;

    if (which == 0) {
      Qs[(size_t)(mb + g * 4 + 0) * 128 + col] = f2bfu(v0);
      Qs[(size_t)(mb + g * 4 + 1) * 128 + col] = f2bfu(v1);
      Qs[(size_t)(mb + g * 4 + 2) * 128 + col] = f2bfu(v2);
      Qs[(size_t)(mb + g * 4 + 3) * 128 + col] = f2bfu(v3);
    } else if (which == 1) {
      const size_t kb = ((size_t)((mb >> 10) * 8 + nt) * 1024 + ((mb & 1023) + g * 4));
      Kt[(kb + 0) * 16 + lm] = f2bfu(v0);
      Kt[(kb + 1) * 16 + lm] = f2bfu(v1);
      Kt[(kb + 2) * 16 + lm] = f2bfu(v2);
      Kt[(kb + 3) * 16 + lm] = f2bfu(v3);
    } else {
      const size_t addr = ((size_t)((mb >> 10) * 8 + nt) * 16 + ((mb & 1023) >> 6)) * 1024
                          + (size_t)lm * 64 + (mb & 63) + g * 4;
      bf16x4 vv;
      vv[0] = (short)f2bfu(v0); vv[1] = (short)f2bfu(v1);
      vv[2] = (short)f2bfu(v2); vv[3] = (short)f2bfu(v3);
      *(bf16x4*)(Vt + addr) = vv;
    }
  }
}

// ---------------------------------------------------------------------------
// Fused attention + output projection (r20-verified, byte-identical).
// One WG = (b, 32-row group); 8 waves = 8 heads; 16 tiles x 64 cols;
// 6 DMAs/wave/tile; counted vmcnt(6); 2 buffers x 48 KB; lsum via MFMA.
// ---------------------------------------------------------------------------
#define BUFB 49152  // per buffer: K 16K | V 16K | adj 8K | edge 8K

__global__ __launch_bounds__(512) void attn_kernel(
    const ushort* __restrict__ Qs, const ushort* __restrict__ Kt,
    const ushort* __restrict__ Vt, const int* __restrict__ adj,
    const float* __restrict__ edge, const float* __restrict__ We,
    const float* __restrict__ Wo, const float* __restrict__ bo,
    float* __restrict__ out) {
  __shared__ __align__(16) char smem[2 * BUFB];

  const int tid = threadIdx.x;
  const int l = tid & 63, h = tid >> 6;
  const int lm = l & 15, g = l >> 4;
  const int b = blockIdx.x >> 5;          // 8 batches
  const int m0 = (blockIdx.x & 31) * 32;  // 32 row-groups of 32 rows

  const float Weh = We[h] * LOG2E;
  bf16x4 qf0 = *(const bf16x4*)(Qs + ((size_t)b * 1024 + m0 + lm) * 128 + h * 16 + g * 4);
  bf16x4 qf1 = *(const bf16x4*)(Qs + ((size_t)b * 1024 + m0 + 16 + lm) * 128 + h * 16 + g * 4);

  const ushort* kt0 = Kt + ((size_t)b * 8 + h) * 16384 + l * 8;
  const int dv = l >> 3, mv = l & 7;
  const int voff = dv * 64 + (((mv * 2) ^ (dv & 6)) * 4);
  const ushort* vt0 = Vt + ((size_t)b * 8 + h) * 16384 + voff;

  const int hh = h & 3;
  const int d0 = hh * 2, d1 = d0 + 1;
  const int row0 = 4 * d0 + (l >> 4), row1 = 4 * d1 + (l >> 4);
  const int gr0 = (l & 15) ^ ((row0 & 7) << 1);
  const int gr1 = (l & 15) ^ ((row1 & 7) << 1);
  const int* sbase = ((h < 4) ? adj : (const int*)edge)
                     + (size_t)b * 1048576 + (size_t)m0 * 1024;
  const int* ssrc0 = sbase + (size_t)row0 * 1024 + gr0 * 4;
  const int* ssrc1 = sbase + (size_t)row1 * 1024 + gr1 * 4;

  char* kdst = smem + h * 2048;
  char* vdst = smem + 16384 + h * 2048;
  char* sreg = smem + ((h < 4) ? 32768 : 40960);
  char* sdst0 = sreg + d0 * 1024;
  char* sdst1 = sreg + d1 * 1024;

  f32x4 oacc0 = {0.f, 0.f, 0.f, 0.f}, oacc1 = {0.f, 0.f, 0.f, 0.f};
  f32x4 lacc0 = {0.f, 0.f, 0.f, 0.f}, lacc1 = {0.f, 0.f, 0.f, 0.f};
  const f32x4 cinit = {-SMAX, -SMAX, -SMAX, -SMAX};
  const short ONE = (short)0x3F80;               // bf16 1.0
  const bf16x4 ones = {ONE, ONE, ONE, ONE};

  auto stage = [&](int T) {
    const int bo_ = (T & 1) * BUFB;
    const ushort* ks = kt0 + (size_t)T * 1024;
    const ushort* vs = vt0 + (size_t)T * 1024;
    dma16(ks,        kdst + bo_);
    dma16(ks + 512,  kdst + bo_ + 1024);
    dma16(vs,        vdst + bo_);
    dma16(vs + 512,  vdst + bo_ + 1024);
    dma16(ssrc0 + T * 64, sdst0 + bo_);
    dma16(ssrc1 + T * 64, sdst1 + bo_);
  };

  auto compute = [&](int bi) {
    const char* base = smem + bi * BUFB;
    const char* kls = base + h * 2048;
    const char* vls = base + 16384 + h * 2048;
    const int* als = (const int*)(base + 32768);
    const int* els = (const int*)(base + 40960);
    const int xorv = (lm & 7) << 3;

    bf16x4 kf[4], vfr[4];
#pragma unroll
    for (int t = 0; t < 4; ++t) {
      kf[t]  = *(const bf16x4*)(kls + (t * 16 + lm) * 32 + g * 8);
      vfr[t] = *(const bf16x4*)(vls + lm * 128 + (((t * 4 + g) ^ (lm & 6)) * 8));
    }
#pragma unroll
    for (int s = 0; s < 2; ++s) {
      const bf16x4 qf = s ? qf1 : qf0;
      f32x4 st[4];
#pragma unroll
      for (int t = 0; t < 4; ++t) st[t] = mfma16(kf[t], qf, cinit);
      f32x4 oac = s ? oacc1 : oacc0;
      f32x4 pac = s ? lacc1 : lacc0;
#pragma unroll
      for (int t = 0; t < 4; ++t) {
        const int ci = (t * 16 + g * 4) ^ xorv;
        const int ro = (16 * s + lm) * 64;
        const i32x4 a4 = *(const i32x4*)(als + ro + ci);
        const i32x4 e4i = *(const i32x4*)(els + ro + ci);
        const f32x4 e4 = *(const f32x4*)&e4i;
        bf16x4 pf4;
#pragma unroll
        for (int j = 0; j < 4; ++j) {
          float p = __builtin_amdgcn_exp2f(fmaf(e4[j], Weh, st[t][j]));
          p = (a4[j] == 0) ? 0.f : p;
          pf4[j] = (short)f2bfu(p);
        }
        oac = mfma16(vfr[t], pf4, oac);   // O^T[d=4g+r][m=lm]
        pac = mfma16(ones,   pf4, pac);   // col-sum of P (all rows equal)
      }
      if (s) { oacc1 = oac; lacc1 = pac; } else { oacc0 = oac; lacc0 = pac; }
    }
  };

  stage(0);
  stage(1);

  for (int ct = 0; ct < 15; ++ct) {
    asm volatile("s_waitcnt vmcnt(6)" ::: "memory");
    __builtin_amdgcn_s_barrier();
    __builtin_amdgcn_sched_barrier(0);
    compute(ct & 1);
    __builtin_amdgcn_s_barrier();
    __builtin_amdgcn_sched_barrier(0);
    if (ct < 14) stage(ct + 2);
  }
  asm volatile("s_waitcnt vmcnt(0)" ::: "memory");
  __builtin_amdgcn_s_barrier();
  __builtin_amdgcn_sched_barrier(0);
  compute(1);

  // ---- epilogue: normalize (lsum = lacc[0]), AO -> LDS, out = AO@Wo + bo ----
  const float inv0 = 1.0f / lacc0[0];
  const float inv1 = 1.0f / lacc1[0];

  __syncthreads();
  ushort* aot = (ushort*)smem;   // 32 x 132 bf16
  {
    bf16x4 ov;
    ov[0] = (short)f2bfu(oacc0[0] * inv0);
    ov[1] = (short)f2bfu(oacc0[1] * inv0);
    ov[2] = (short)f2bfu(oacc0[2] * inv0);
    ov[3] = (short)f2bfu(oacc0[3] * inv0);
    *(bf16x4*)(aot + (lm) * 132 + h * 16 + g * 4) = ov;
    ov[0] = (short)f2bfu(oacc1[0] * inv1);
    ov[1] = (short)f2bfu(oacc1[1] * inv1);
    ov[2] = (short)f2bfu(oacc1[2] * inv1);
    ov[3] = (short)f2bfu(oacc1[3] * inv1);
    *(bf16x4*)(aot + (16 + lm) * 132 + h * 16 + g * 4) = ov;
  }
  __syncthreads();

  f32x4 acc0 = {0.f, 0.f, 0.f, 0.f}, acc1 = {0.f, 0.f, 0.f, 0.f};
#pragma unroll
  for (int ks = 0; ks < 8; ++ks) {
    const float* wp = Wo + (size_t)(ks * 16 + g * 4) * 128 + h * 16 + lm;
    bf16x4 bfr;
    bfr[0] = (short)f2bfu(wp[0]);   bfr[1] = (short)f2bfu(wp[128]);
    bfr[2] = (short)f2bfu(wp[256]); bfr[3] = (short)f2bfu(wp[384]);
    bf16x4 a0 = *(const bf16x4*)(aot + lm * 132 + ks * 16 + g * 4);
    bf16x4 a1 = *(const bf16x4*)(aot + (16 + lm) * 132 + ks * 16 + g * 4);
    acc0 = mfma16(a0, bfr, acc0);
    acc1 = mfma16(a1, bfr, acc1);
  }
  const float bv = bo[h * 16 + lm];
  float* op0 = out + ((size_t)b * 1024 + m0 + g * 4) * 128 + h * 16 + lm;
  float* op1 = op0 + 16 * 128;
  op0[0 * 128] = acc0[0] + bv;
  op0[1 * 128] = acc0[1] + bv;
  op0[2 * 128] = acc0[2] + bv;
  op0[3 * 128] = acc0[3] + bv;
  op1[0 * 128] = acc1[0] + bv;
  op1[1 * 128] = acc1[1] + bv;
  op1[2 * 128] = acc1[2] + bv;
  op1[3 * 128] = acc1[3] + bv;
}

extern "C" void kernel_launch(void* const* d_in, const int* in_sizes, int n_in,
                              void* d_out, int out_size, void* d_ws, size_t ws_size,
                              hipStream_t stream) {
  const float* x   = (const float*)d_in[0];
  const int*   adj = (const int*)d_in[1];
  const float* ew  = (const float*)d_in[2];
  const float* Wq  = (const float*)d_in[3];
  const float* bq  = (const float*)d_in[4];
  const float* Wk  = (const float*)d_in[5];
  const float* bk  = (const float*)d_in[6];
  const float* Wv  = (const float*)d_in[7];
  const float* bv  = (const float*)d_in[8];
  const float* Wo  = (const float*)d_in[9];
  const float* bo  = (const float*)d_in[10];
  const float* We  = (const float*)d_in[11];
  // be (d_in[12]) dropped: softmax(x + c) == softmax(x)

  const size_t MN = (size_t)8 * 1024 * 128;  // 1M elements
  ushort* Qs = (ushort*)d_ws;
  ushort* Kt = Qs + MN;
  ushort* Vt = Kt + MN;

  gemm_qkv<<<1536, 256, 0, stream>>>(x, Wq, bq, Wk, bk, Wv, bv, Qs, Kt, Vt);
  attn_kernel<<<256, 512, 0, stream>>>(Qs, Kt, Vt, adj, ew, We, Wo, bo, (float*)d_out);
}

// Round 23
// 49.679 us; speedup vs baseline: 1.1364x; 1.0082x over previous
//
#include <hip/hip_runtime.h>
#include <hip/hip_bf16.h>

typedef __attribute__((ext_vector_type(4))) short bf16x4;   // 4 bf16 = 2 VGPR
typedef __attribute__((ext_vector_type(4))) float f32x4;
typedef __attribute__((ext_vector_type(4))) int i32x4;

#define LOG2E 1.4426950408889634f
#define SMAX 8.0f   // fixed softmax shift (log2 domain); exact after normalization

static __device__ inline f32x4 mfma16(bf16x4 a, bf16x4 b, f32x4 c) {
  return __builtin_amdgcn_mfma_f32_16x16x16bf16_1k(a, b, c, 0, 0, 0);
}
static __device__ inline ushort f2bfu(float f) {
  __hip_bfloat16 h = __float2bfloat16(f);
  return *(ushort*)&h;
}
static __device__ __forceinline__ void dma16(const void* g, void* l) {
  __builtin_amdgcn_global_load_lds(
      (const __attribute__((address_space(1))) void*)g,
      (__attribute__((address_space(3))) void*)l, 16, 0, 0);
}

// ---------------------------------------------------------------------------
// Fused QKV projections. DELTA vs r22: each wave computes FOUR row-subtiles
// (rows mt4*64 + {0,16,32,48}) for one column tile -> B-fragment built once
// per 4 MFMAs. grid 768 x 256 (3 slices x 256 blocks; 4 tasks/block).
// Q: row-major scaled 0.25*log2e. K: Kt[((b8+h)*1024+n)*16+k].
// V: Vt[((b8+h)*16+(n>>6))*1024 + d*64 + (n&63)].
// ---------------------------------------------------------------------------
__global__ __launch_bounds__(256) void gemm_qkv(
    const float* __restrict__ x,
    const float* __restrict__ Wq, const float* __restrict__ bq,
    const float* __restrict__ Wk, const float* __restrict__ bk,
    const float* __restrict__ Wv, const float* __restrict__ bv,
    ushort* __restrict__ Qs, ushort* __restrict__ Kt, ushort* __restrict__ Vt) {
  const int which = blockIdx.x >> 8;        // 0=Q 1=K 2=V (256 blocks each)
  const int bid = blockIdx.x & 255;
  const int tid = threadIdx.x;
  const int l = tid & 63, w = tid >> 6;
  const int lm = l & 15, g = l >> 4;
  const int task = bid * 4 + w;             // 0..1023
  const int mt4 = task >> 3, nt = task & 7; // 128 row-quads x 8 col tiles
  const int rbase = mt4 * 64 + lm;
  const int col = nt * 16 + lm;

  const float* W = (which == 0) ? Wq : (which == 1) ? Wk : Wv;
  const float* bias = (which == 0) ? bq : (which == 1) ? bk : bv;

  f32x4 acc[4];
  acc[0] = acc[1] = acc[2] = acc[3] = f32x4{0.f, 0.f, 0.f, 0.f};
#pragma unroll
  for (int ks = 0; ks < 8; ++ks) {
    const float* wp = W + (size_t)(ks * 16 + g * 4) * 128 + col;
    bf16x4 bfr;
    bfr[0] = (short)f2bfu(wp[0]);   bfr[1] = (short)f2bfu(wp[128]);
    bfr[2] = (short)f2bfu(wp[256]); bfr[3] = (short)f2bfu(wp[384]);
#pragma unroll
    for (int s = 0; s < 4; ++s) {
      f32x4 av = *(const f32x4*)(x + (size_t)(rbase + s * 16) * 128 + ks * 16 + g * 4);
      bf16x4 a;
      a[0] = (short)f2bfu(av[0]); a[1] = (short)f2bfu(av[1]);
      a[2] = (short)f2bfu(av[2]); a[3] = (short)f2bfu(av[3]);
      acc[s] = mfma16(a, bfr, acc[s]);
    }
  }
  const float bv_ = bias[col];
  const float alpha = (which == 0) ? 0.25f * LOG2E : 1.0f;

#pragma unroll
  for (int s = 0; s < 4; ++s) {
    const int mb = mt4 * 64 + s * 16;
    float v0 = (acc[s][0] + bv_) * alpha, v1 = (acc[s][1] + bv_) * alpha;
    float v2 = (acc[s][2] + bv_) * alpha, v3 = (acc[s][3] + bv_) * alpha;

    if (which == 0) {
      Qs[(size_t)(mb + g * 4 + 0) * 128 + col] = f2bfu(v0);
      Qs[(size_t)(mb + g * 4 + 1) * 128 + col] = f2bfu(v1);
      Qs[(size_t)(mb + g * 4 + 2) * 128 + col] = f2bfu(v2);
      Qs[(size_t)(mb + g * 4 + 3) * 128 + col] = f2bfu(v3);
    } else if (which == 1) {
      const size_t kb = ((size_t)((mb >> 10) * 8 + nt) * 1024 + ((mb & 1023) + g * 4));
      Kt[(kb + 0) * 16 + lm] = f2bfu(v0);
      Kt[(kb + 1) * 16 + lm] = f2bfu(v1);
      Kt[(kb + 2) * 16 + lm] = f2bfu(v2);
      Kt[(kb + 3) * 16 + lm] = f2bfu(v3);
    } else {
      const size_t addr = ((size_t)((mb >> 10) * 8 + nt) * 16 + ((mb & 1023) >> 6)) * 1024
                          + (size_t)lm * 64 + (mb & 63) + g * 4;
      bf16x4 vv;
      vv[0] = (short)f2bfu(v0); vv[1] = (short)f2bfu(v1);
      vv[2] = (short)f2bfu(v2); vv[3] = (short)f2bfu(v3);
      *(bf16x4*)(Vt + addr) = vv;
    }
  }
}

// ---------------------------------------------------------------------------
// Fused attention + output projection (r20/r22-verified, byte-identical).
// One WG = (b, 32-row group); 8 waves = 8 heads; 16 tiles x 64 cols;
// 6 DMAs/wave/tile; counted vmcnt(6); 2 buffers x 48 KB; lsum via MFMA.
// ---------------------------------------------------------------------------
#define BUFB 49152  // per buffer: K 16K | V 16K | adj 8K | edge 8K

__global__ __launch_bounds__(512) void attn_kernel(
    const ushort* __restrict__ Qs, const ushort* __restrict__ Kt,
    const ushort* __restrict__ Vt, const int* __restrict__ adj,
    const float* __restrict__ edge, const float* __restrict__ We,
    const float* __restrict__ Wo, const float* __restrict__ bo,
    float* __restrict__ out) {
  __shared__ __align__(16) char smem[2 * BUFB];

  const int tid = threadIdx.x;
  const int l = tid & 63, h = tid >> 6;
  const int lm = l & 15, g = l >> 4;
  const int b = blockIdx.x >> 5;          // 8 batches
  const int m0 = (blockIdx.x & 31) * 32;  // 32 row-groups of 32 rows

  const float Weh = We[h] * LOG2E;
  bf16x4 qf0 = *(const bf16x4*)(Qs + ((size_t)b * 1024 + m0 + lm) * 128 + h * 16 + g * 4);
  bf16x4 qf1 = *(const bf16x4*)(Qs + ((size_t)b * 1024 + m0 + 16 + lm) * 128 + h * 16 + g * 4);

  const ushort* kt0 = Kt + ((size_t)b * 8 + h) * 16384 + l * 8;
  const int dv = l >> 3, mv = l & 7;
  const int voff = dv * 64 + (((mv * 2) ^ (dv & 6)) * 4);
  const ushort* vt0 = Vt + ((size_t)b * 8 + h) * 16384 + voff;

  const int hh = h & 3;
  const int d0 = hh * 2, d1 = d0 + 1;
  const int row0 = 4 * d0 + (l >> 4), row1 = 4 * d1 + (l >> 4);
  const int gr0 = (l & 15) ^ ((row0 & 7) << 1);
  const int gr1 = (l & 15) ^ ((row1 & 7) << 1);
  const int* sbase = ((h < 4) ? adj : (const int*)edge)
                     + (size_t)b * 1048576 + (size_t)m0 * 1024;
  const int* ssrc0 = sbase + (size_t)row0 * 1024 + gr0 * 4;
  const int* ssrc1 = sbase + (size_t)row1 * 1024 + gr1 * 4;

  char* kdst = smem + h * 2048;
  char* vdst = smem + 16384 + h * 2048;
  char* sreg = smem + ((h < 4) ? 32768 : 40960);
  char* sdst0 = sreg + d0 * 1024;
  char* sdst1 = sreg + d1 * 1024;

  f32x4 oacc0 = {0.f, 0.f, 0.f, 0.f}, oacc1 = {0.f, 0.f, 0.f, 0.f};
  f32x4 lacc0 = {0.f, 0.f, 0.f, 0.f}, lacc1 = {0.f, 0.f, 0.f, 0.f};
  const f32x4 cinit = {-SMAX, -SMAX, -SMAX, -SMAX};
  const short ONE = (short)0x3F80;               // bf16 1.0
  const bf16x4 ones = {ONE, ONE, ONE, ONE};

  auto stage = [&](int T) {
    const int bo_ = (T & 1) * BUFB;
    const ushort* ks = kt0 + (size_t)T * 1024;
    const ushort* vs = vt0 + (size_t)T * 1024;
    dma16(ks,        kdst + bo_);
    dma16(ks + 512,  kdst + bo_ + 1024);
    dma16(vs,        vdst + bo_);
    dma16(vs + 512,  vdst + bo_ + 1024);
    dma16(ssrc0 + T * 64, sdst0 + bo_);
    dma16(ssrc1 + T * 64, sdst1 + bo_);
  };

  auto compute = [&](int bi) {
    const char* base = smem + bi * BUFB;
    const char* kls = base + h * 2048;
    const char* vls = base + 16384 + h * 2048;
    const int* als = (const int*)(base + 32768);
    const int* els = (const int*)(base + 40960);
    const int xorv = (lm & 7) << 3;

    bf16x4 kf[4], vfr[4];
#pragma unroll
    for (int t = 0; t < 4; ++t) {
      kf[t]  = *(const bf16x4*)(kls + (t * 16 + lm) * 32 + g * 8);
      vfr[t] = *(const bf16x4*)(vls + lm * 128 + (((t * 4 + g) ^ (lm & 6)) * 8));
    }
#pragma unroll
    for (int s = 0; s < 2; ++s) {
      const bf16x4 qf = s ? qf1 : qf0;
      f32x4 st[4];
#pragma unroll
      for (int t = 0; t < 4; ++t) st[t] = mfma16(kf[t], qf, cinit);
      f32x4 oac = s ? oacc1 : oacc0;
      f32x4 pac = s ? lacc1 : lacc0;
#pragma unroll
      for (int t = 0; t < 4; ++t) {
        const int ci = (t * 16 + g * 4) ^ xorv;
        const int ro = (16 * s + lm) * 64;
        const i32x4 a4 = *(const i32x4*)(als + ro + ci);
        const i32x4 e4i = *(const i32x4*)(els + ro + ci);
        const f32x4 e4 = *(const f32x4*)&e4i;
        bf16x4 pf4;
#pragma unroll
        for (int j = 0; j < 4; ++j) {
          float p = __builtin_amdgcn_exp2f(fmaf(e4[j], Weh, st[t][j]));
          p = (a4[j] == 0) ? 0.f : p;
          pf4[j] = (short)f2bfu(p);
        }
        oac = mfma16(vfr[t], pf4, oac);   // O^T[d=4g+r][m=lm]
        pac = mfma16(ones,   pf4, pac);   // col-sum of P (all rows equal)
      }
      if (s) { oacc1 = oac; lacc1 = pac; } else { oacc0 = oac; lacc0 = pac; }
    }
  };

  stage(0);
  stage(1);

  for (int ct = 0; ct < 15; ++ct) {
    asm volatile("s_waitcnt vmcnt(6)" ::: "memory");
    __builtin_amdgcn_s_barrier();
    __builtin_amdgcn_sched_barrier(0);
    compute(ct & 1);
    __builtin_amdgcn_s_barrier();
    __builtin_amdgcn_sched_barrier(0);
    if (ct < 14) stage(ct + 2);
  }
  asm volatile("s_waitcnt vmcnt(0)" ::: "memory");
  __builtin_amdgcn_s_barrier();
  __builtin_amdgcn_sched_barrier(0);
  compute(1);

  // ---- epilogue: normalize (lsum = lacc[0]), AO -> LDS, out = AO@Wo + bo ----
  const float inv0 = 1.0f / lacc0[0];
  const float inv1 = 1.0f / lacc1[0];

  __syncthreads();
  ushort* aot = (ushort*)smem;   // 32 x 132 bf16
  {
    bf16x4 ov;
    ov[0] = (short)f2bfu(oacc0[0] * inv0);
    ov[1] = (short)f2bfu(oacc0[1] * inv0);
    ov[2] = (short)f2bfu(oacc0[2] * inv0);
    ov[3] = (short)f2bfu(oacc0[3] * inv0);
    *(bf16x4*)(aot + (lm) * 132 + h * 16 + g * 4) = ov;
    ov[0] = (short)f2bfu(oacc1[0] * inv1);
    ov[1] = (short)f2bfu(oacc1[1] * inv1);
    ov[2] = (short)f2bfu(oacc1[2] * inv1);
    ov[3] = (short)f2bfu(oacc1[3] * inv1);
    *(bf16x4*)(aot + (16 + lm) * 132 + h * 16 + g * 4) = ov;
  }
  __syncthreads();

  f32x4 acc0 = {0.f, 0.f, 0.f, 0.f}, acc1 = {0.f, 0.f, 0.f, 0.f};
#pragma unroll
  for (int ks = 0; ks < 8; ++ks) {
    const float* wp = Wo + (size_t)(ks * 16 + g * 4) * 128 + h * 16 + lm;
    bf16x4 bfr;
    bfr[0] = (short)f2bfu(wp[0]);   bfr[1] = (short)f2bfu(wp[128]);
    bfr[2] = (short)f2bfu(wp[256]); bfr[3] = (short)f2bfu(wp[384]);
    bf16x4 a0 = *(const bf16x4*)(aot + lm * 132 + ks * 16 + g * 4);
    bf16x4 a1 = *(const bf16x4*)(aot + (16 + lm) * 132 + ks * 16 + g * 4);
    acc0 = mfma16(a0, bfr, acc0);
    acc1 = mfma16(a1, bfr, acc1);
  }
  const float bv = bo[h * 16 + lm];
  float* op0 = out + ((size_t)b * 1024 + m0 + g * 4) * 128 + h * 16 + lm;
  float* op1 = op0 + 16 * 128;
  op0[0 * 128] = acc0[0] + bv;
  op0[1 * 128] = acc0[1] + bv;
  op0[2 * 128] = acc0[2] + bv;
  op0[3 * 128] = acc0[3] + bv;
  op1[0 * 128] = acc1[0] + bv;
  op1[1 * 128] = acc1[1] + bv;
  op1[2 * 128] = acc1[2] + bv;
  op1[3 * 128] = acc1[3] + bv;
}

extern "C" void kernel_launch(void* const* d_in, const int* in_sizes, int n_in,
                              void* d_out, int out_size, void* d_ws, size_t ws_size,
                              hipStream_t stream) {
  const float* x   = (const float*)d_in[0];
  const int*   adj = (const int*)d_in[1];
  const float* ew  = (const float*)d_in[2];
  const float* Wq  = (const float*)d_in[3];
  const float* bq  = (const float*)d_in[4];
  const float* Wk  = (const float*)d_in[5];
  const float* bk  = (const float*)d_in[6];
  const float* Wv  = (const float*)d_in[7];
  const float* bv  = (const float*)d_in[8];
  const float* Wo  = (const float*)d_in[9];
  const float* bo  = (const float*)d_in[10];
  const float* We  = (const float*)d_in[11];
  // be (d_in[12]) dropped: softmax(x + c) == softmax(x)

  const size_t MN = (size_t)8 * 1024 * 128;  // 1M elements
  ushort* Qs = (ushort*)d_ws;
  ushort* Kt = Qs + MN;
  ushort* Vt = Kt + MN;

  gemm_qkv<<<768, 256, 0, stream>>>(x, Wq, bq, Wk, bk, Wv, bv, Qs, Kt, Vt);
  attn_kernel<<<256, 512, 0, stream>>>(Qs, Kt, Vt, adj, ew, We, Wo, bo, (float*)d_out);
}

// Round 24
// 48.491 us; speedup vs baseline: 1.1642x; 1.0245x over previous
//
#include <hip/hip_runtime.h>
#include <hip/hip_bf16.h>

typedef __attribute__((ext_vector_type(4))) short bf16x4;   // 4 bf16 = 2 VGPR
typedef __attribute__((ext_vector_type(4))) float f32x4;
typedef __attribute__((ext_vector_type(4))) int i32x4;

#define LOG2E 1.4426950408889634f
#define SMAX 8.0f   // fixed softmax shift (log2 domain); exact after normalization

static __device__ inline f32x4 mfma16(bf16x4 a, bf16x4 b, f32x4 c) {
  return __builtin_amdgcn_mfma_f32_16x16x16bf16_1k(a, b, c, 0, 0, 0);
}
static __device__ inline ushort f2bfu(float f) {
  __hip_bfloat16 h = __float2bfloat16(f);
  return *(ushort*)&h;
}
static __device__ __forceinline__ void dma16(const void* g, void* l) {
  __builtin_amdgcn_global_load_lds(
      (const __attribute__((address_space(1))) void*)g,
      (__attribute__((address_space(3))) void*)l, 16, 0, 0);
}

// ---------------------------------------------------------------------------
// Fused QKV projections (r23-verified, byte-identical). grid 768 x 256.
// Each wave: FOUR row-subtiles per column tile (B-fragment amortized x4).
// ---------------------------------------------------------------------------
__global__ __launch_bounds__(256) void gemm_qkv(
    const float* __restrict__ x,
    const float* __restrict__ Wq, const float* __restrict__ bq,
    const float* __restrict__ Wk, const float* __restrict__ bk,
    const float* __restrict__ Wv, const float* __restrict__ bv,
    ushort* __restrict__ Qs, ushort* __restrict__ Kt, ushort* __restrict__ Vt) {
  const int which = blockIdx.x >> 8;        // 0=Q 1=K 2=V (256 blocks each)
  const int bid = blockIdx.x & 255;
  const int tid = threadIdx.x;
  const int l = tid & 63, w = tid >> 6;
  const int lm = l & 15, g = l >> 4;
  const int task = bid * 4 + w;             // 0..1023
  const int mt4 = task >> 3, nt = task & 7; // 128 row-quads x 8 col tiles
  const int rbase = mt4 * 64 + lm;
  const int col = nt * 16 + lm;

  const float* W = (which == 0) ? Wq : (which == 1) ? Wk : Wv;
  const float* bias = (which == 0) ? bq : (which == 1) ? bk : bv;

  f32x4 acc[4];
  acc[0] = acc[1] = acc[2] = acc[3] = f32x4{0.f, 0.f, 0.f, 0.f};
#pragma unroll
  for (int ks = 0; ks < 8; ++ks) {
    const float* wp = W + (size_t)(ks * 16 + g * 4) * 128 + col;
    bf16x4 bfr;
    bfr[0] = (short)f2bfu(wp[0]);   bfr[1] = (short)f2bfu(wp[128]);
    bfr[2] = (short)f2bfu(wp[256]); bfr[3] = (short)f2bfu(wp[384]);
#pragma unroll
    for (int s = 0; s < 4; ++s) {
      f32x4 av = *(const f32x4*)(x + (size_t)(rbase + s * 16) * 128 + ks * 16 + g * 4);
      bf16x4 a;
      a[0] = (short)f2bfu(av[0]); a[1] = (short)f2bfu(av[1]);
      a[2] = (short)f2bfu(av[2]); a[3] = (short)f2bfu(av[3]);
      acc[s] = mfma16(a, bfr, acc[s]);
    }
  }
  const float bv_ = bias[col];
  const float alpha = (which == 0) ? 0.25f * LOG2E : 1.0f;

#pragma unroll
  for (int s = 0; s < 4; ++s) {
    const int mb = mt4 * 64 + s * 16;
    float v0 = (acc[s][0] + bv_) * alpha, v1 = (acc[s][1] + bv_) * alpha;
    float v2 = (acc[s][2] + bv_) * alpha, v3 = (acc[s][3] + bv_) * alpha;

    if (which == 0) {
      Qs[(size_t)(mb + g * 4 + 0) * 128 + col] = f2bfu(v0);
      Qs[(size_t)(mb + g * 4 + 1) * 128 + col] = f2bfu(v1);
      Qs[(size_t)(mb + g * 4 + 2) * 128 + col] = f2bfu(v2);
      Qs[(size_t)(mb + g * 4 + 3) * 128 + col] = f2bfu(v3);
    } else if (which == 1) {
      const size_t kb = ((size_t)((mb >> 10) * 8 + nt) * 1024 + ((mb & 1023) + g * 4));
      Kt[(kb + 0) * 16 + lm] = f2bfu(v0);
      Kt[(kb + 1) * 16 + lm] = f2bfu(v1);
      Kt[(kb + 2) * 16 + lm] = f2bfu(v2);
      Kt[(kb + 3) * 16 + lm] = f2bfu(v3);
    } else {
      const size_t addr = ((size_t)((mb >> 10) * 8 + nt) * 16 + ((mb & 1023) >> 6)) * 1024
                          + (size_t)lm * 64 + (mb & 63) + g * 4;
      bf16x4 vv;
      vv[0] = (short)f2bfu(v0); vv[1] = (short)f2bfu(v1);
      vv[2] = (short)f2bfu(v2); vv[3] = (short)f2bfu(v3);
      *(bf16x4*)(Vt + addr) = vv;
    }
  }
}

// ---------------------------------------------------------------------------
// Fused attention + output projection. DELTA vs r20/r23: 3 buffers x 48 KB
// (144 KB), SINGLE barrier per iteration, stage(ct+2) issued BEFORE compute
// (r9's proven schedule at the 32-row tile scale). Race-free: stage(ct+2)
// writes buf (ct+2)%3, last read by compute(ct-1) whose LDS reads complete
// before that wave reaches this iteration's barrier. vmcnt(6) constant.
// ---------------------------------------------------------------------------
#define BUFB 49152  // per buffer: K 16K | V 16K | adj 8K | edge 8K

__global__ __launch_bounds__(512) void attn_kernel(
    const ushort* __restrict__ Qs, const ushort* __restrict__ Kt,
    const ushort* __restrict__ Vt, const int* __restrict__ adj,
    const float* __restrict__ edge, const float* __restrict__ We,
    const float* __restrict__ Wo, const float* __restrict__ bo,
    float* __restrict__ out) {
  __shared__ __align__(16) char smem[3 * BUFB];

  const int tid = threadIdx.x;
  const int l = tid & 63, h = tid >> 6;
  const int lm = l & 15, g = l >> 4;
  const int b = blockIdx.x >> 5;          // 8 batches
  const int m0 = (blockIdx.x & 31) * 32;  // 32 row-groups of 32 rows

  const float Weh = We[h] * LOG2E;
  bf16x4 qf0 = *(const bf16x4*)(Qs + ((size_t)b * 1024 + m0 + lm) * 128 + h * 16 + g * 4);
  bf16x4 qf1 = *(const bf16x4*)(Qs + ((size_t)b * 1024 + m0 + 16 + lm) * 128 + h * 16 + g * 4);

  const ushort* kt0 = Kt + ((size_t)b * 8 + h) * 16384 + l * 8;
  const int dv = l >> 3, mv = l & 7;
  const int voff = dv * 64 + (((mv * 2) ^ (dv & 6)) * 4);
  const ushort* vt0 = Vt + ((size_t)b * 8 + h) * 16384 + voff;

  const int hh = h & 3;
  const int d0 = hh * 2, d1 = d0 + 1;
  const int row0 = 4 * d0 + (l >> 4), row1 = 4 * d1 + (l >> 4);
  const int gr0 = (l & 15) ^ ((row0 & 7) << 1);
  const int gr1 = (l & 15) ^ ((row1 & 7) << 1);
  const int* sbase = ((h < 4) ? adj : (const int*)edge)
                     + (size_t)b * 1048576 + (size_t)m0 * 1024;
  const int* ssrc0 = sbase + (size_t)row0 * 1024 + gr0 * 4;
  const int* ssrc1 = sbase + (size_t)row1 * 1024 + gr1 * 4;

  char* kdst = smem + h * 2048;
  char* vdst = smem + 16384 + h * 2048;
  char* sreg = smem + ((h < 4) ? 32768 : 40960);
  char* sdst0 = sreg + d0 * 1024;
  char* sdst1 = sreg + d1 * 1024;

  f32x4 oacc0 = {0.f, 0.f, 0.f, 0.f}, oacc1 = {0.f, 0.f, 0.f, 0.f};
  f32x4 lacc0 = {0.f, 0.f, 0.f, 0.f}, lacc1 = {0.f, 0.f, 0.f, 0.f};
  const f32x4 cinit = {-SMAX, -SMAX, -SMAX, -SMAX};
  const short ONE = (short)0x3F80;               // bf16 1.0
  const bf16x4 ones = {ONE, ONE, ONE, ONE};

  auto stage = [&](int T) {
    const int bo_ = (T % 3) * BUFB;
    const ushort* ks = kt0 + (size_t)T * 1024;
    const ushort* vs = vt0 + (size_t)T * 1024;
    dma16(ks,        kdst + bo_);
    dma16(ks + 512,  kdst + bo_ + 1024);
    dma16(vs,        vdst + bo_);
    dma16(vs + 512,  vdst + bo_ + 1024);
    dma16(ssrc0 + T * 64, sdst0 + bo_);
    dma16(ssrc1 + T * 64, sdst1 + bo_);
  };

  auto compute = [&](int bi) {
    const char* base = smem + bi * BUFB;
    const char* kls = base + h * 2048;
    const char* vls = base + 16384 + h * 2048;
    const int* als = (const int*)(base + 32768);
    const int* els = (const int*)(base + 40960);
    const int xorv = (lm & 7) << 3;

    bf16x4 kf[4], vfr[4];
#pragma unroll
    for (int t = 0; t < 4; ++t) {
      kf[t]  = *(const bf16x4*)(kls + (t * 16 + lm) * 32 + g * 8);
      vfr[t] = *(const bf16x4*)(vls + lm * 128 + (((t * 4 + g) ^ (lm & 6)) * 8));
    }
#pragma unroll
    for (int s = 0; s < 2; ++s) {
      const bf16x4 qf = s ? qf1 : qf0;
      f32x4 st[4];
#pragma unroll
      for (int t = 0; t < 4; ++t) st[t] = mfma16(kf[t], qf, cinit);
      f32x4 oac = s ? oacc1 : oacc0;
      f32x4 pac = s ? lacc1 : lacc0;
#pragma unroll
      for (int t = 0; t < 4; ++t) {
        const int ci = (t * 16 + g * 4) ^ xorv;
        const int ro = (16 * s + lm) * 64;
        const i32x4 a4 = *(const i32x4*)(als + ro + ci);
        const i32x4 e4i = *(const i32x4*)(els + ro + ci);
        const f32x4 e4 = *(const f32x4*)&e4i;
        bf16x4 pf4;
#pragma unroll
        for (int j = 0; j < 4; ++j) {
          float p = __builtin_amdgcn_exp2f(fmaf(e4[j], Weh, st[t][j]));
          p = (a4[j] == 0) ? 0.f : p;
          pf4[j] = (short)f2bfu(p);
        }
        oac = mfma16(vfr[t], pf4, oac);   // O^T[d=4g+r][m=lm]
        pac = mfma16(ones,   pf4, pac);   // col-sum of P (all rows equal)
      }
      if (s) { oacc1 = oac; lacc1 = pac; } else { oacc0 = oac; lacc0 = pac; }
    }
  };

  // prologue: tiles 0,1 in flight (12 DMAs/wave)
  stage(0);
  stage(1);

  for (int ct = 0; ct < 16; ++ct) {
    // own tile-ct DMAs landed; tile ct+1's 6 remain in flight
    if (ct < 15) asm volatile("s_waitcnt vmcnt(6)" ::: "memory");
    else         asm volatile("s_waitcnt vmcnt(0)" ::: "memory");
    __builtin_amdgcn_s_barrier();
    __builtin_amdgcn_sched_barrier(0);
    if (ct < 14) stage(ct + 2);        // buf (ct+2)%3: free (see header note)
    __builtin_amdgcn_sched_barrier(0);
    compute(ct % 3);
  }

  // ---- epilogue: normalize (lsum = lacc[0]), AO -> LDS, out = AO@Wo + bo ----
  const float inv0 = 1.0f / lacc0[0];
  const float inv1 = 1.0f / lacc1[0];

  __syncthreads();               // all waves done with buffer reads
  ushort* aot = (ushort*)smem;   // 32 x 132 bf16 (buf0; tile15 used buf0 -> synced)
  {
    bf16x4 ov;
    ov[0] = (short)f2bfu(oacc0[0] * inv0);
    ov[1] = (short)f2bfu(oacc0[1] * inv0);
    ov[2] = (short)f2bfu(oacc0[2] * inv0);
    ov[3] = (short)f2bfu(oacc0[3] * inv0);
    *(bf16x4*)(aot + (lm) * 132 + h * 16 + g * 4) = ov;
    ov[0] = (short)f2bfu(oacc1[0] * inv1);
    ov[1] = (short)f2bfu(oacc1[1] * inv1);
    ov[2] = (short)f2bfu(oacc1[2] * inv1);
    ov[3] = (short)f2bfu(oacc1[3] * inv1);
    *(bf16x4*)(aot + (16 + lm) * 132 + h * 16 + g * 4) = ov;
  }
  __syncthreads();

  f32x4 acc0 = {0.f, 0.f, 0.f, 0.f}, acc1 = {0.f, 0.f, 0.f, 0.f};
#pragma unroll
  for (int ks = 0; ks < 8; ++ks) {
    const float* wp = Wo + (size_t)(ks * 16 + g * 4) * 128 + h * 16 + lm;
    bf16x4 bfr;
    bfr[0] = (short)f2bfu(wp[0]);   bfr[1] = (short)f2bfu(wp[128]);
    bfr[2] = (short)f2bfu(wp[256]); bfr[3] = (short)f2bfu(wp[384]);
    bf16x4 a0 = *(const bf16x4*)(aot + lm * 132 + ks * 16 + g * 4);
    bf16x4 a1 = *(const bf16x4*)(aot + (16 + lm) * 132 + ks * 16 + g * 4);
    acc0 = mfma16(a0, bfr, acc0);
    acc1 = mfma16(a1, bfr, acc1);
  }
  const float bv = bo[h * 16 + lm];
  float* op0 = out + ((size_t)b * 1024 + m0 + g * 4) * 128 + h * 16 + lm;
  float* op1 = op0 + 16 * 128;
  op0[0 * 128] = acc0[0] + bv;
  op0[1 * 128] = acc0[1] + bv;
  op0[2 * 128] = acc0[2] + bv;
  op0[3 * 128] = acc0[3] + bv;
  op1[0 * 128] = acc1[0] + bv;
  op1[1 * 128] = acc1[1] + bv;
  op1[2 * 128] = acc1[2] + bv;
  op1[3 * 128] = acc1[3] + bv;
}

extern "C" void kernel_launch(void* const* d_in, const int* in_sizes, int n_in,
                              void* d_out, int out_size, void* d_ws, size_t ws_size,
                              hipStream_t stream) {
  const float* x   = (const float*)d_in[0];
  const int*   adj = (const int*)d_in[1];
  const float* ew  = (const float*)d_in[2];
  const float* Wq  = (const float*)d_in[3];
  const float* bq  = (const float*)d_in[4];
  const float* Wk  = (const float*)d_in[5];
  const float* bk  = (const float*)d_in[6];
  const float* Wv  = (const float*)d_in[7];
  const float* bv  = (const float*)d_in[8];
  const float* Wo  = (const float*)d_in[9];
  const float* bo  = (const float*)d_in[10];
  const float* We  = (const float*)d_in[11];
  // be (d_in[12]) dropped: softmax(x + c) == softmax(x)

  const size_t MN = (size_t)8 * 1024 * 128;  // 1M elements
  ushort* Qs = (ushort*)d_ws;
  ushort* Kt = Qs + MN;
  ushort* Vt = Kt + MN;

  gemm_qkv<<<768, 256, 0, stream>>>(x, Wq, bq, Wk, bk, Wv, bv, Qs, Kt, Vt);
  attn_kernel<<<256, 512, 0, stream>>>(Qs, Kt, Vt, adj, ew, We, Wo, bo, (float*)d_out);
}